// Round 1
// baseline (467.662 us; speedup 1.0000x reference)
//
#include <hip/hip_runtime.h>

// PolicyNetGCN: 2-layer GCN + linear head on MI355X.
// Pipeline per call:
//   1. build CSR from (edge_row, edge_col, edge_weight)   [cheap, ~30us]
//   2. gemm_k: flat = state^T . W1 + b1                    [n,256]
//   3. spmm_k: agg = relu(A . flat)                        [n,256]  (CSR gather, no atomics)
//   4. gemm_k: flat = agg . W2 + b2
//   5. spmm_k: agg = relu(A . flat)
//   6. head_k: out[b,n] = agg[n,b,:] . w_out

__global__ __launch_bounds__(256) void count_k(const int* __restrict__ row,
                                               int* __restrict__ cnt, int E) {
    int e = blockIdx.x * 256 + threadIdx.x;
    if (e < E) atomicAdd(&cnt[row[e]], 1);
}

__global__ __launch_bounds__(1024) void scanA(const int* __restrict__ cnt,
                                              int* __restrict__ excl,
                                              int* __restrict__ bsum, int n) {
    __shared__ int tmp[1024];
    int i = blockIdx.x * 1024 + threadIdx.x;
    int v = (i < n) ? cnt[i] : 0;
    tmp[threadIdx.x] = v;
    __syncthreads();
    for (int off = 1; off < 1024; off <<= 1) {
        int t = (threadIdx.x >= (unsigned)off) ? tmp[threadIdx.x - off] : 0;
        __syncthreads();
        tmp[threadIdx.x] += t;
        __syncthreads();
    }
    if (i < n) excl[i] = tmp[threadIdx.x] - v;   // local exclusive
    if (threadIdx.x == 1023) bsum[blockIdx.x] = tmp[1023];
}

__global__ void scanB(int* bsum, int nb) {
    if (threadIdx.x == 0 && blockIdx.x == 0) {
        int run = 0;
        for (int i = 0; i < nb; ++i) { int v = bsum[i]; bsum[i] = run; run += v; }
    }
}

__global__ __launch_bounds__(1024) void scanC(int* __restrict__ excl,
                                              const int* __restrict__ bsum,
                                              int* __restrict__ cursor, int n) {
    int i = blockIdx.x * 1024 + threadIdx.x;
    if (i < n) { int v = excl[i] + bsum[blockIdx.x]; excl[i] = v; cursor[i] = v; }
}

__global__ __launch_bounds__(256) void fill_k(const int* __restrict__ row,
                                              const int* __restrict__ col,
                                              const float* __restrict__ w,
                                              int* __restrict__ cursor,
                                              int* __restrict__ scol,
                                              float* __restrict__ sw, int E) {
    int e = blockIdx.x * 256 + threadIdx.x;
    if (e < E) {
        int pos = atomicAdd(&cursor[row[e]], 1);
        scol[pos] = col[e];
        sw[pos]   = w[e];
    }
}

// support[n, wave*64+lane] = bias[lane] + sum_k x[n,wave,k] * W[k,lane]
// wave (=batch idx) made wave-uniform so x-row loads become scalar loads.
// Each thread holds its W column (64 floats) in VGPRs across the node loop.
__global__ __launch_bounds__(256) void gemm_k(const float* __restrict__ x,
                                              const float* __restrict__ W,
                                              const float* __restrict__ bias,
                                              float* __restrict__ out,
                                              int N, int layer1) {
    int wave = __builtin_amdgcn_readfirstlane(threadIdx.x >> 6);
    int lane = threadIdx.x & 63;
    float wcol[64];
#pragma unroll
    for (int k = 0; k < 64; ++k) wcol[k] = W[k * 64 + lane];
    float bi = bias[lane];
    size_t base   = layer1 ? ((size_t)wave * N * 64) : ((size_t)wave * 64);
    size_t stride = layer1 ? 64 : 256;
    for (int n = blockIdx.x; n < N; n += gridDim.x) {
        const float* row = x + base + (size_t)n * stride;
        float a0 = 0.f, a1 = 0.f, a2 = 0.f, a3 = 0.f;
#pragma unroll
        for (int k = 0; k < 64; k += 4) {
            a0 += row[k + 0] * wcol[k + 0];
            a1 += row[k + 1] * wcol[k + 1];
            a2 += row[k + 2] * wcol[k + 2];
            a3 += row[k + 3] * wcol[k + 3];
        }
        out[(size_t)n * 256 + wave * 64 + lane] = bi + ((a0 + a1) + (a2 + a3));
    }
}

// One wave per output row: acc[lane*4..lane*4+3] over edges of this row.
// Per edge: uniform scol/sw load + one coalesced 1KB row gather (float4/lane).
__global__ __launch_bounds__(256) void spmm_k(const float* __restrict__ flat,
                                              const int* __restrict__ rp,
                                              const int* __restrict__ scol,
                                              const float* __restrict__ sw,
                                              float* __restrict__ out, int N) {
    int wave = threadIdx.x >> 6, lane = threadIdx.x & 63;
    int rowi = blockIdx.x * 4 + wave;
    if (rowi >= N) return;
    int s = rp[rowi], e = rp[rowi + 1];
    float ax = 0.f, ay = 0.f, az = 0.f, aw = 0.f;
    const float4* flat4 = (const float4*)flat;
    for (int j = s; j < e; ++j) {
        int c = scol[j];
        float wt = sw[j];
        float4 v = flat4[(size_t)c * 64 + lane];
        ax += wt * v.x; ay += wt * v.y; az += wt * v.z; aw += wt * v.w;
    }
    float4 r;
    r.x = fmaxf(ax, 0.f); r.y = fmaxf(ay, 0.f);
    r.z = fmaxf(az, 0.f); r.w = fmaxf(aw, 0.f);
    ((float4*)out)[(size_t)rowi * 64 + lane] = r;
}

// out[b*N + n] = sum_d agg[n*256 + b*64 + d] * w_out[d]
__global__ __launch_bounds__(256) void head_k(const float* __restrict__ agg,
                                              const float* __restrict__ wout,
                                              float* __restrict__ out, int N) {
    __shared__ float ws[64];
    if (threadIdx.x < 64) ws[threadIdx.x] = wout[threadIdx.x];
    __syncthreads();
    int t = blockIdx.x * 256 + threadIdx.x;
    if (t < N * 4) {
        int n = t >> 2, b = t & 3;
        const float4* row = (const float4*)(agg + (size_t)t * 64);
        float acc = 0.f;
#pragma unroll
        for (int i = 0; i < 16; ++i) {
            float4 v = row[i];
            acc += v.x * ws[4 * i] + v.y * ws[4 * i + 1] +
                   v.z * ws[4 * i + 2] + v.w * ws[4 * i + 3];
        }
        out[(size_t)b * N + n] = acc;
    }
}

extern "C" void kernel_launch(void* const* d_in, const int* in_sizes, int n_in,
                              void* d_out, int out_size, void* d_ws, size_t ws_size,
                              hipStream_t stream) {
    const float* state = (const float*)d_in[0];
    const int*   erow  = (const int*)d_in[1];
    const int*   ecol  = (const int*)d_in[2];
    const float* ew    = (const float*)d_in[3];
    const float* W1    = (const float*)d_in[4];
    const float* b1    = (const float*)d_in[5];
    const float* W2    = (const float*)d_in[6];
    const float* b2    = (const float*)d_in[7];
    const float* wout  = (const float*)d_in[8];
    float* out = (float*)d_out;

    int N = in_sizes[0] / (4 * 64);  // 50000
    int E = in_sizes[1];             // 800000

    char* ws = (char*)d_ws;
    size_t off = 0;
    auto alloc = [&](size_t bytes) -> char* {
        char* p = ws + off;
        off += (bytes + 255) & ~(size_t)255;
        return p;
    };
    float* flat = (float*)alloc((size_t)N * 256 * 4);
    float* agg  = (float*)alloc((size_t)N * 256 * 4);
    int*   cnt  = (int*)alloc((size_t)(N + 1) * 4);
    int*   rp   = (int*)alloc((size_t)(N + 1) * 4);
    int*   cur  = (int*)alloc((size_t)(N + 1) * 4);
    int*   bsum = (int*)alloc(256 * 4);
    int*   scol = (int*)alloc((size_t)E * 4);
    float* sw   = (float*)alloc((size_t)E * 4);
    if (off > ws_size) return;  // workspace too small; bench will flag it

    // --- CSR build ---
    hipMemsetAsync(cnt, 0, (size_t)(N + 1) * 4, stream);
    count_k<<<(E + 255) / 256, 256, 0, stream>>>(erow, cnt, E);
    int nscan = N + 1;
    int nblk  = (nscan + 1023) / 1024;  // 49
    scanA<<<nblk, 1024, 0, stream>>>(cnt, rp, bsum, nscan);
    scanB<<<1, 64, 0, stream>>>(bsum, nblk);
    scanC<<<nblk, 1024, 0, stream>>>(rp, bsum, cur, nscan);
    fill_k<<<(E + 255) / 256, 256, 0, stream>>>(erow, ecol, ew, cur, scol, sw, E);

    // --- layer 1 ---
    gemm_k<<<2048, 256, 0, stream>>>(state, W1, b1, flat, N, 1);
    spmm_k<<<(N + 3) / 4, 256, 0, stream>>>(flat, rp, scol, sw, agg, N);
    // --- layer 2 ---
    gemm_k<<<2048, 256, 0, stream>>>(agg, W2, b2, flat, N, 0);
    spmm_k<<<(N + 3) / 4, 256, 0, stream>>>(flat, rp, scol, sw, agg, N);
    // --- head ---
    head_k<<<(N * 4 + 255) / 256, 256, 0, stream>>>(agg, wout, out, N);
}